// Round 11
// baseline (49.805 us; speedup 1.0000x reference)
//
#include <hip/hip_runtime.h>

// Implicit-GEMM MFMA conv, round 11: R5 machinery + 2-step X-walk.
//  - prep_all: (a) x f32 -> bf16 pre-swizzled xb (4096 blocks)
//              (b) K' 19-tap bf16 B-frags kw (19 blocks), sc folded into center tap
//  - conv_walk2: block walks X in {2Xc, 2Xc+1}. LDS = 3 plane slots
//    [y10=10][zp=34][ci=32] bf16 (21760 B each, 65280 total, 2 blk/CU).
//    Staging via async global_load_lds FROM XB (L2-resident: 2 MB/batch/XCD).
//    Plane X0+2 streams into the freed slot under taps 5..18 of X0.
//    M=64/wave, depth-3 size-4 B-ring, batched A ds_reads, R5 scatter epilogue.
//  - conv_fb: fallback if ws too small (R5's reg-staged f32 path, full tile).

typedef __attribute__((ext_vector_type(8))) short bf16x8;
typedef __attribute__((ext_vector_type(4))) float f32x4;
typedef unsigned int u32;

__device__ constexpr int TAt[19] = {1,3,4,5,7,9,10,11,12,13,14,15,16,17,19,21,22,23,25};

__device__ __forceinline__ float sus_f(float v) { return v > 0.f ? __expf(-1.f / v) : 0.f; }

__device__ __forceinline__ unsigned short f2bf(float f) {
    union { float f; unsigned u; } c; c.f = f;
    unsigned u = c.u;
    u += 0x7FFFu + ((u >> 16) & 1u);          // round-to-nearest-even
    return (unsigned short)(u >> 16);
}

// ---------------- fused precompute (identical to R5) ----------------
__global__ __launch_bounds__(256) void prep_all(
    const float* __restrict__ x,
    const float* __restrict__ w_lin0, const float* __restrict__ w_lin1,
    const float* __restrict__ w000,  const float* __restrict__ w011,
    const float* __restrict__ w101,  const float* __restrict__ w110,
    unsigned short* __restrict__ xb, unsigned short* __restrict__ kw,
    int koff)
{
    const int bid = blockIdx.x;
    const int tid = threadIdx.x;

    if (bid < koff) {
        const int gi = bid * 256 + tid;          // 16B-group id
        const int vox = gi >> 2, g = gi & 3;
        const int gz = vox & 31;
        const float4* sp = reinterpret_cast<const float4*>(x) + (size_t)gi * 2;
        const float4 lo = sp[0], hi = sp[1];
        bf16x8 w;
        w[0] = (short)f2bf(lo.x); w[1] = (short)f2bf(lo.y);
        w[2] = (short)f2bf(lo.z); w[3] = (short)f2bf(lo.w);
        w[4] = (short)f2bf(hi.x); w[5] = (short)f2bf(hi.y);
        w[6] = (short)f2bf(hi.z); w[7] = (short)f2bf(hi.w);
        const int slot = g ^ (((gz + 1) >> 1) & 3);
        const size_t dst = ((size_t)(vox >> 5) << 10) + (gz << 5) + (slot << 3);
        *reinterpret_cast<bf16x8*>(xb + dst) = w;
        return;
    }

    const int ta = bid - koff;
    const int t = TAt[ta];
    const int a = t / 9, b = (t / 3) % 3, c = t % 3;

    const float fx = (float)(a - 1), fy = (float)(b - 1), fz = (float)(c - 1);
    const float dist = sqrtf(fx * fx + fy * fy + fz * fz);
    float emb[4];
    #pragma unroll
    for (int r = 0; r < 4; ++r) {
        const float v = 0.3f * (float)(r + 1);
        const float d = (dist - v) * (1.0f / 0.3f);
        emb[r] = 8.4335731f * sus_f(d + 1.f) * sus_f(1.f - d);
    }
    const float s = (dist > 0.f) ? (1.7320508f / dist) : 0.f;
    const float shv[3] = { fx * s, fy * s, fz * s };
    const float S000 = 0.25f / 27.f;
    const float S1   = 0.25f * 0.57735027f / 27.f;
    const float LNRM = 0.35355339f;

    const int ci = tid >> 3;
    #pragma unroll
    for (int j = 0; j < 8; ++j) {
        const int o = (tid & 7) * 8 + j;
        float val;
        if (ci < 8) {
            const int u = ci;
            if (o < 16) {
                const float* p = w000 + u * 16 + o;
                val = S000 * (emb[0]*p[0] + emb[1]*p[128] + emb[2]*p[256] + emb[3]*p[384]);
                if (t == 13) val += LNRM * w_lin0[u * 16 + o];
            } else {
                const int oo = o - 16, w = oo / 3, m = oo % 3;
                const float* p = w011 + u * 16 + w;
                val = S1 * shv[m] * (emb[0]*p[0] + emb[1]*p[128] + emb[2]*p[256] + emb[3]*p[384]);
            }
        } else {
            const int iu = ci - 8, u = iu / 3, ic = iu % 3;
            if (o < 16) {
                const float* p = w110 + u * 16 + o;
                val = S1 * shv[ic] * (emb[0]*p[0] + emb[1]*p[128] + emb[2]*p[256] + emb[3]*p[384]);
            } else {
                const int oo = o - 16, w = oo / 3, m = oo % 3;
                if (ic == m) {
                    const float* p = w101 + u * 16 + w;
                    val = S1 * (emb[0]*p[0] + emb[1]*p[128] + emb[2]*p[256] + emb[3]*p[384]);
                    if (t == 13) val += LNRM * w_lin1[u * 16 + w];
                } else {
                    val = 0.f;
                }
            }
        }
        const int g = ci >> 3, slot = ci & 7, nt = o >> 4, cc = o & 15;
        const int lane = (g << 4) | cc;
        kw[((size_t)(ta * 4 + nt) * 64 + lane) * 8 + slot] = f2bf(val);
    }
}

// ---------------- tap-range helper (audited in R8; fully unrolled) ----------------
template<int LO, int HI>
__device__ __forceinline__ void tap_range(
    const char* lxc, const bf16x8* kwf, int l, int lr, int lg, int yloc,
    int s0, int s1, int s2, bf16x8 (&bring)[4][4], f32x4 (&acc)[4][4])
{
    #pragma unroll
    for (int ta = LO; ta < HI; ++ta) {
        const int t = TAt[ta];
        const int a = t / 9, b = (t / 3) % 3, c = t % 3;

        if (ta + 3 < 19) {
            #pragma unroll
            for (int nt = 0; nt < 4; ++nt)
                bring[(ta + 3) & 3][nt] = kwf[(size_t)((ta + 3) * 4 + nt) * 64 + l];
        }

        const int sbase = (a == 0 ? s0 : (a == 1 ? s1 : s2)) * 21760;
        bf16x8 af[4];
        #pragma unroll
        for (int r = 0; r < 4; ++r) {
            const int y10 = yloc + (r >> 1) + b;
            const int zp = 16 * (r & 1) + lr + c;
            af[r] = *reinterpret_cast<const bf16x8*>(
                lxc + sbase + (y10 * 34 + zp) * 64 + ((lg ^ ((zp >> 1) & 3)) << 4));
        }
        #pragma unroll
        for (int r = 0; r < 4; ++r)
            #pragma unroll
            for (int nt = 0; nt < 4; ++nt)
                acc[r][nt] = __builtin_amdgcn_mfma_f32_16x16x32_bf16(
                    af[r], bring[ta & 3][nt], acc[r][nt], 0, 0, 0);
    }
}

// ---------------- main conv kernel: 2-step X walk, DIRECT xb staging ----------------
__global__ __launch_bounds__(256, 2) void conv_walk2(
    const unsigned short* __restrict__ xb,
    const unsigned short* __restrict__ kw,
    float* __restrict__ out)
{
    __shared__ unsigned short lx[3 * 10 * 34 * 32];   // 3 slots x 21760 B

    const int tid = threadIdx.x;
    const int bid = blockIdx.x;
    // XCD swizzle: grid 512, bid&7 = XCD -> XCD owns batch n (xb slice 2MB, L2-fit).
    const int n = bid & 7;
    const int idx = bid >> 3;                 // 0..63
    const int Xc = idx >> 2, Yg = idx & 3;
    const int X0 = Xc * 2;
    const int Y0 = Yg * 8;
    const int wid = tid >> 6, l = tid & 63, lr = l & 15, lg = l >> 4;
    const int yloc = wid * 2;

    const bf16x8* kwf = reinterpret_cast<const bf16x8*>(kw);
    char* lxc = reinterpret_cast<char*>(lx);

    bf16x8 bring[4][4];
    auto ring_preload = [&]() {
        #pragma unroll
        for (int p = 0; p < 3; ++p)
            #pragma unroll
            for (int nt = 0; nt < 4; ++nt)
                bring[p][nt] = kwf[(size_t)(p * 4 + nt) * 64 + l];
    };

    // async stage of one x-plane p (from xb) into LDS slot s: 10 rows x 2048B
    auto stage_direct = [&](int p, int s) {
        #pragma unroll
        for (int k = 0; k < 3; ++k) {
            const int rr = wid + (k << 2);
            if (rr < 10) {
                const int gy = Y0 + rr - 1;
                char* dstrow = lxc + s * 21760 + rr * 2176 + 64;
                if ((unsigned)p < 32u && (unsigned)gy < 32u) {
                    const char* src = reinterpret_cast<const char*>(xb) +
                        ((size_t)((n * 32 + p) * 32 + gy) << 11);
                    __builtin_amdgcn_global_load_lds(
                        (const __attribute__((address_space(1))) u32*)(src + l * 16),
                        (__attribute__((address_space(3))) u32*)(dstrow), 16, 0, 0);
                    __builtin_amdgcn_global_load_lds(
                        (const __attribute__((address_space(1))) u32*)(src + 1024 + l * 16),
                        (__attribute__((address_space(3))) u32*)(dstrow + 1024), 16, 0, 0);
                } else {
                    bf16x8 zz = (bf16x8)(short)0;
                    *reinterpret_cast<bf16x8*>(dstrow + l * 16) = zz;
                    *reinterpret_cast<bf16x8*>(dstrow + 1024 + l * 16) = zz;
                }
            }
        }
    };

    auto epilogue = [&](int X, f32x4 (&acc)[4][4]) {    // R5 unswapped layout
        float* ob = out + ((size_t)(((n * 32 + X) * 32 + Y0 + yloc) * 32) << 6);
        #pragma unroll
        for (int r = 0; r < 4; ++r) {
            float* oy = ob + (size_t)(r >> 1) * 2048;
            #pragma unroll
            for (int nt = 0; nt < 4; ++nt)
                #pragma unroll
                for (int reg = 0; reg < 4; ++reg) {
                    const int z = 16 * (r & 1) + 4 * lg + reg;
                    oy[z * 64 + nt * 16 + lr] = acc[r][nt][reg];
                }
        }
    };

    // slot map: sm holds X0-1 then X0+2; s0 holds X0; s1 holds X0+1
    const int sm = (X0 + 2) % 3;
    const int s0 = X0 % 3;
    const int s1 = (X0 + 1) % 3;

    ring_preload();                           // B loads issue first
    // zero pads (zp=0 / zp=33) of all 3 slots: 3 x 10 rows x 2
    if (tid < 60) {
        const int s = tid / 20, rem = tid % 20;
        const int rr = rem >> 1, zp = (rem & 1) * 33;
        f32x4* dp = reinterpret_cast<f32x4*>(lxc + s * 21760 + rr * 2176 + zp * 64);
        #pragma unroll
        for (int q = 0; q < 4; ++q) dp[q] = (f32x4)0.f;
    }
    stage_direct(X0 - 1, sm);
    stage_direct(X0,     s0);
    stage_direct(X0 + 1, s1);
    __syncthreads();                          // vmcnt0: all three planes resident

    // ---- X0 ----
    f32x4 acc[4][4];
    #pragma unroll
    for (int r = 0; r < 4; ++r)
        #pragma unroll
        for (int nt = 0; nt < 4; ++nt) acc[r][nt] = (f32x4)0.f;

    tap_range<0, 5>(lxc, kwf, l, lr, lg, yloc, sm, s0, s1, bring, acc);  // a=0 taps
    __syncthreads();                          // slot sm released by all waves
    stage_direct(X0 + 2, sm);                 // async: flies under taps 5..18
    tap_range<5, 19>(lxc, kwf, l, lr, lg, yloc, sm, s0, s1, bring, acc); // a=1,2 only
    ring_preload();                           // taps 0..2 for X1 (after X0 ring reads)
    epilogue(X0, acc);
    __syncthreads();                          // vmcnt0: plane X0+2 visible

    // ---- X1 = X0+1 (planes: a=0 -> s0(X0), a=1 -> s1(X1), a=2 -> sm(X2)) ----
    #pragma unroll
    for (int r = 0; r < 4; ++r)
        #pragma unroll
        for (int nt = 0; nt < 4; ++nt) acc[r][nt] = (f32x4)0.f;

    tap_range<0, 19>(lxc, kwf, l, lr, lg, yloc, s0, s1, sm, bring, acc);
    epilogue(X0 + 1, acc);
}

// ---------------- fallback: R5 reg-staged full-tile kernel ----------------
__global__ __launch_bounds__(256, 2) void conv_fb(
    const float* __restrict__ x,
    const unsigned short* __restrict__ kw,
    float* __restrict__ out)
{
    __shared__ unsigned short lx[3 * 10 * 34 * 32];

    const int tid = threadIdx.x;
    const int bid = blockIdx.x;
    const int xcd = bid & 7, idx = bid >> 3;
    const int gid = xcd * 128 + idx;
    const int n = gid >> 7, X = (gid >> 2) & 31, Yg = gid & 3;
    const int Y0 = Yg * 8;
    const int wid = tid >> 6, l = tid & 63, lr = l & 15, lg = l >> 4;

    const bf16x8* kwf = reinterpret_cast<const bf16x8*>(kw);

    bf16x8 bring[4][4];
    #pragma unroll
    for (int p = 0; p < 3; ++p)
        #pragma unroll
        for (int nt = 0; nt < 4; ++nt)
            bring[p][nt] = kwf[(size_t)(p * 4 + nt) * 64 + l];

    if (tid < 60) {
        const int row = tid >> 1, zp = (tid & 1) * 33;
        f32x4* dp = reinterpret_cast<f32x4*>(
            reinterpret_cast<char*>(lx) + row * 2176 + zp * 64);
        #pragma unroll
        for (int q = 0; q < 4; ++q) dp[q] = (f32x4)0.f;
    }

    for (int it = tid; it < 960; it += 256) {
        const int dx = it / 320, rem = it - dx * 320;
        const int y6 = rem >> 5, z = rem & 31;
        const int gx = X + dx - 1, gy = Y0 + y6 - 1;
        char* row = reinterpret_cast<char*>(lx) + (dx * 10 + y6) * 2176 + (z + 1) * 64;
        if ((unsigned)gx < 32u && (unsigned)gy < 32u) {
            const float4* sp = reinterpret_cast<const float4*>(
                x + ((size_t)(((n * 32 + gx) * 32 + gy) * 32 + z) << 5));
            const int swz = ((z + 1) >> 1) & 3;
            #pragma unroll
            for (int g = 0; g < 4; ++g) {
                const float4 lo = sp[2 * g], hi = sp[2 * g + 1];
                bf16x8 w;
                w[0] = (short)f2bf(lo.x); w[1] = (short)f2bf(lo.y);
                w[2] = (short)f2bf(lo.z); w[3] = (short)f2bf(lo.w);
                w[4] = (short)f2bf(hi.x); w[5] = (short)f2bf(hi.y);
                w[6] = (short)f2bf(hi.z); w[7] = (short)f2bf(hi.w);
                *reinterpret_cast<bf16x8*>(row + ((g ^ swz) << 4)) = w;
            }
        } else {
            bf16x8 zz = (bf16x8)(short)0;
            #pragma unroll
            for (int g = 0; g < 4; ++g)
                *reinterpret_cast<bf16x8*>(row + (g << 4)) = zz;
        }
    }
    __syncthreads();

    const char* lxc = reinterpret_cast<const char*>(lx);
    const int yloc = wid * 2;

    f32x4 acc[4][4];
    #pragma unroll
    for (int r = 0; r < 4; ++r)
        #pragma unroll
        for (int nt = 0; nt < 4; ++nt) acc[r][nt] = (f32x4)0.f;

    tap_range<0, 19>(lxc, kwf, l, lr, lg, yloc, 0, 1, 2, bring, acc);

    float* ob = out + ((size_t)(((n * 32 + X) * 32 + Y0 + yloc) * 32) << 6);
    #pragma unroll
    for (int r = 0; r < 4; ++r) {
        float* oy = ob + (size_t)(r >> 1) * 2048;
        #pragma unroll
        for (int nt = 0; nt < 4; ++nt)
            #pragma unroll
            for (int reg = 0; reg < 4; ++reg) {
                const int z = 16 * (r & 1) + 4 * lg + reg;
                oy[z * 64 + nt * 16 + lr] = acc[r][nt][reg];
            }
    }
}

extern "C" void kernel_launch(void* const* d_in, const int* in_sizes, int n_in,
                              void* d_out, int out_size, void* d_ws, size_t ws_size,
                              hipStream_t stream) {
    const float* x    = (const float*)d_in[0];
    const float* wl0  = (const float*)d_in[1];
    const float* wl1  = (const float*)d_in[2];
    const float* w000 = (const float*)d_in[3];
    const float* w011 = (const float*)d_in[4];
    const float* w101 = (const float*)d_in[5];
    const float* w110 = (const float*)d_in[6];
    float* out = (float*)d_out;

    unsigned short* kw = (unsigned short*)d_ws;
    const size_t KWB = 77824;               // 19*4*64*8*2
    const size_t XBB = 16777216ull;         // 8*32^3*32*2

    if (ws_size >= KWB + XBB) {
        unsigned short* xb = (unsigned short*)((char*)d_ws + KWB);
        prep_all<<<dim3(4096 + 19), dim3(256), 0, stream>>>(
            x, wl0, wl1, w000, w011, w101, w110, xb, kw, 4096);
        conv_walk2<<<dim3(512), dim3(256), 0, stream>>>(xb, kw, out);
    } else {
        prep_all<<<dim3(19), dim3(256), 0, stream>>>(
            x, wl0, wl1, w000, w011, w101, w110, nullptr, kw, 0);
        conv_fb<<<dim3(1024), dim3(256), 0, stream>>>(x, kw, out);
    }
}

// Round 12
// 42.660 us; speedup vs baseline: 1.1675x; 1.1675x over previous
//
#include <hip/hip_runtime.h>

// Implicit-GEMM MFMA conv — FINAL (= round-5 config, best measured: 42.4 us).
//  - prep_all: (a) x f32 -> bf16 pre-swizzled xb (4096 blocks)
//              (b) K' 19-tap bf16 B-frags kw (19 blocks), sc folded into center tap
//  - conv_mfma<true>: Yg=8 tile (LDS 65280B, 2 blk/CU), async global_load_lds
//    staging from xb, M=64/wave, depth-3 prefetch into size-4 B-frag register
//    ring, batched A ds_reads, pad-only zeroing, XCD-aware bid swizzle.
//  - conv_mfma<false>: fallback if ws too small (reg-staged f32->bf16).
//
// Ledger (total us): R5=42.4 BEST | fused=44.0 | swap-epi=46.0 | walk-xb=49.8
//   | nt-stores=51.1 | small-tile=53.5 | walk-f32=62.6.
// Residual ~2.3x over the ~18us HBM-traffic floor is intra-kernel phase
// serialization (2 lockstep blocks/CU); all single-change attacks regressed.

typedef __attribute__((ext_vector_type(8))) short bf16x8;
typedef __attribute__((ext_vector_type(4))) float f32x4;
typedef unsigned int u32;

__device__ __forceinline__ float sus_f(float v) { return v > 0.f ? __expf(-1.f / v) : 0.f; }

__device__ __forceinline__ unsigned short f2bf(float f) {
    union { float f; unsigned u; } c; c.f = f;
    unsigned u = c.u;
    u += 0x7FFFu + ((u >> 16) & 1u);          // round-to-nearest-even
    return (unsigned short)(u >> 16);
}

// ---------------- fused precompute ----------------
// xb layout: per (n,gx,gy) row: 32 z * 4 slots * 8 elems; group g stored at
//   slot = g ^ (((z+1)>>1)&3)
// kw layout (bf16): frag[ta][nt][lane=64][slot=8]
//   value = K[t][ci = 8*(lane>>4) + slot][o = 16*nt + (lane&15)]
__global__ __launch_bounds__(256) void prep_all(
    const float* __restrict__ x,
    const float* __restrict__ w_lin0, const float* __restrict__ w_lin1,
    const float* __restrict__ w000,  const float* __restrict__ w011,
    const float* __restrict__ w101,  const float* __restrict__ w110,
    unsigned short* __restrict__ xb, unsigned short* __restrict__ kw,
    int koff)
{
    const int bid = blockIdx.x;
    const int tid = threadIdx.x;

    if (bid < koff) {
        // ---- x conversion ----
        const int gi = bid * 256 + tid;          // 16B-group id
        const int vox = gi >> 2, g = gi & 3;
        const int gz = vox & 31;
        const float4* sp = reinterpret_cast<const float4*>(x) + (size_t)gi * 2;
        const float4 lo = sp[0], hi = sp[1];
        bf16x8 w;
        w[0] = (short)f2bf(lo.x); w[1] = (short)f2bf(lo.y);
        w[2] = (short)f2bf(lo.z); w[3] = (short)f2bf(lo.w);
        w[4] = (short)f2bf(hi.x); w[5] = (short)f2bf(hi.y);
        w[6] = (short)f2bf(hi.z); w[7] = (short)f2bf(hi.w);
        const int slot = g ^ (((gz + 1) >> 1) & 3);
        const size_t dst = ((size_t)(vox >> 5) << 10) + (gz << 5) + (slot << 3);
        *reinterpret_cast<bf16x8*>(xb + dst) = w;
        return;
    }

    // ---- K' fragments ----
    const int taps[19] = {1,3,4,5,7,9,10,11,12,13,14,15,16,17,19,21,22,23,25};
    const int ta = bid - koff;
    const int t = taps[ta];
    const int a = t / 9, b = (t / 3) % 3, c = t % 3;

    const float fx = (float)(a - 1), fy = (float)(b - 1), fz = (float)(c - 1);
    const float dist = sqrtf(fx * fx + fy * fy + fz * fz);
    float emb[4];
    #pragma unroll
    for (int r = 0; r < 4; ++r) {
        const float v = 0.3f * (float)(r + 1);
        const float d = (dist - v) * (1.0f / 0.3f);
        emb[r] = 8.4335731f * sus_f(d + 1.f) * sus_f(1.f - d);
    }
    const float s = (dist > 0.f) ? (1.7320508f / dist) : 0.f;
    const float shv[3] = { fx * s, fy * s, fz * s };
    const float S000 = 0.25f / 27.f;
    const float S1   = 0.25f * 0.57735027f / 27.f;
    const float LNRM = 0.35355339f;

    const int ci = tid >> 3;
    #pragma unroll
    for (int j = 0; j < 8; ++j) {
        const int o = (tid & 7) * 8 + j;
        float val;
        if (ci < 8) {
            const int u = ci;
            if (o < 16) {
                const float* p = w000 + u * 16 + o;
                val = S000 * (emb[0]*p[0] + emb[1]*p[128] + emb[2]*p[256] + emb[3]*p[384]);
                if (t == 13) val += LNRM * w_lin0[u * 16 + o];
            } else {
                const int oo = o - 16, w = oo / 3, m = oo % 3;
                const float* p = w011 + u * 16 + w;
                val = S1 * shv[m] * (emb[0]*p[0] + emb[1]*p[128] + emb[2]*p[256] + emb[3]*p[384]);
            }
        } else {
            const int iu = ci - 8, u = iu / 3, ic = iu % 3;
            if (o < 16) {
                const float* p = w110 + u * 16 + o;
                val = S1 * shv[ic] * (emb[0]*p[0] + emb[1]*p[128] + emb[2]*p[256] + emb[3]*p[384]);
            } else {
                const int oo = o - 16, w = oo / 3, m = oo % 3;
                if (ic == m) {
                    const float* p = w101 + u * 16 + w;
                    val = S1 * (emb[0]*p[0] + emb[1]*p[128] + emb[2]*p[256] + emb[3]*p[384]);
                    if (t == 13) val += LNRM * w_lin1[u * 16 + w];
                } else {
                    val = 0.f;
                }
            }
        }
        const int g = ci >> 3, slot = ci & 7, nt = o >> 4, cc = o & 15;
        const int lane = (g << 4) | cc;
        kw[((size_t)(ta * 4 + nt) * 64 + lane) * 8 + slot] = f2bf(val);
    }
}

// ---------------- main conv kernel ----------------
// LDS tile: [dx=3][y10=10][zp=34][ci=32] bf16 (zp 0/33 are zero pads), 65280 B.
// Within a (dx,y10,zp) row, 16B ci-groups stored at slot ^ ((zp>>1)&3).
template<bool DIRECT>
__global__ __launch_bounds__(256, 2) void conv_mfma(
    const float* __restrict__ x,
    const unsigned short* __restrict__ xb,
    const unsigned short* __restrict__ kw,
    float* __restrict__ out)
{
    __shared__ unsigned short lx[3 * 10 * 34 * 32];   // 65280 B

    const int tid = threadIdx.x;
    const int bid = blockIdx.x;
    // XCD swizzle: bid&7 = XCD; each XCD owns one batch n, X sweeping sequentially.
    const int xcd = bid & 7, idx = bid >> 3;
    const int gid = xcd * 128 + idx;
    const int n = gid >> 7, X = (gid >> 2) & 31, Yg = gid & 3;
    const int Y0 = Yg * 8;
    const int wid = tid >> 6, l = tid & 63, lr = l & 15, lg = l >> 4;

    const bf16x8* kwf = reinterpret_cast<const bf16x8*>(kw);

    // ---- B-frag ring preload (taps 0..2 into slots 0..2); slot ta&3 is
    // consumed at iter ta, slot (ta+3)&3 refilled at iter ta -> never aliases.
    bf16x8 bring[4][4];
    #pragma unroll
    for (int p = 0; p < 3; ++p)
        #pragma unroll
        for (int nt = 0; nt < 4; ++nt)
            bring[p][nt] = kwf[(size_t)(p * 4 + nt) * 64 + l];

    // ---- zero pad slots only (zp=0 and zp=33 of each of the 30 rows) ----
    if (tid < 60) {
        const int row = tid >> 1, zp = (tid & 1) * 33;
        f32x4* dp = reinterpret_cast<f32x4*>(
            reinterpret_cast<char*>(lx) + row * 2176 + zp * 64);
        #pragma unroll
        for (int q = 0; q < 4; ++q) dp[q] = (f32x4)0.f;
    }

    if (DIRECT) {
        // async staging: 30 rows, each = 2048B contiguous in xb and in LDS
        #pragma unroll
        for (int k = 0; k < 8; ++k) {
            const int rr = wid + (k << 2);
            if (rr < 30) {
                const int dx = rr / 10, y6 = rr - dx * 10;
                const int gx = X + dx - 1, gy = Y0 + y6 - 1;
                char* dstrow = reinterpret_cast<char*>(lx) + rr * 2176 + 64;
                if ((unsigned)gx < 32u && (unsigned)gy < 32u) {
                    const char* src = reinterpret_cast<const char*>(xb) +
                        ((size_t)((n * 32 + gx) * 32 + gy) << 11);
                    __builtin_amdgcn_global_load_lds(
                        (const __attribute__((address_space(1))) u32*)(src + l * 16),
                        (__attribute__((address_space(3))) u32*)(dstrow), 16, 0, 0);
                    __builtin_amdgcn_global_load_lds(
                        (const __attribute__((address_space(1))) u32*)(src + 1024 + l * 16),
                        (__attribute__((address_space(3))) u32*)(dstrow + 1024), 16, 0, 0);
                } else {
                    bf16x8 zz = (bf16x8)(short)0;
                    *reinterpret_cast<bf16x8*>(dstrow + l * 16) = zz;
                    *reinterpret_cast<bf16x8*>(dstrow + 1024 + l * 16) = zz;
                }
            }
        }
    } else {
        // fallback: reg-staged f32 -> bf16, same swizzled layout
        for (int it = tid; it < 960; it += 256) {
            const int dx = it / 320, rem = it - dx * 320;
            const int y6 = rem >> 5, z = rem & 31;
            const int gx = X + dx - 1, gy = Y0 + y6 - 1;
            char* row = reinterpret_cast<char*>(lx) + (dx * 10 + y6) * 2176 + (z + 1) * 64;
            if ((unsigned)gx < 32u && (unsigned)gy < 32u) {
                const float4* sp = reinterpret_cast<const float4*>(
                    x + ((size_t)(((n * 32 + gx) * 32 + gy) * 32 + z) << 5));
                const int swz = ((z + 1) >> 1) & 3;
                #pragma unroll
                for (int g = 0; g < 4; ++g) {
                    const float4 lo = sp[2 * g], hi = sp[2 * g + 1];
                    bf16x8 w;
                    w[0] = (short)f2bf(lo.x); w[1] = (short)f2bf(lo.y);
                    w[2] = (short)f2bf(lo.z); w[3] = (short)f2bf(lo.w);
                    w[4] = (short)f2bf(hi.x); w[5] = (short)f2bf(hi.y);
                    w[6] = (short)f2bf(hi.z); w[7] = (short)f2bf(hi.w);
                    *reinterpret_cast<bf16x8*>(row + ((g ^ swz) << 4)) = w;
                }
            } else {
                bf16x8 zz = (bf16x8)(short)0;
                #pragma unroll
                for (int g = 0; g < 4; ++g)
                    *reinterpret_cast<bf16x8*>(row + (g << 4)) = zz;
            }
        }
    }
    __syncthreads();

    // ---- barrier-free tap loop; wave owns y-pair (Y0+2*wid, +1), M=64 ----
    constexpr int TA[19] = {1,3,4,5,7,9,10,11,12,13,14,15,16,17,19,21,22,23,25};
    const char* lxc = reinterpret_cast<const char*>(lx);
    const int yloc = wid * 2;

    f32x4 acc[4][4];
    #pragma unroll
    for (int r = 0; r < 4; ++r)
        #pragma unroll
        for (int nt = 0; nt < 4; ++nt) acc[r][nt] = (f32x4)0.f;

    #pragma unroll
    for (int ta = 0; ta < 19; ++ta) {
        const int t = TA[ta];
        const int a = t / 9, b = (t / 3) % 3, c = t % 3;

        // refill ring slot (ta+3)&3 for tap ta+3 (static index after unroll;
        // distinct from consumed slot ta&3)
        if (ta + 3 < 19) {
            #pragma unroll
            for (int nt = 0; nt < 4; ++nt)
                bring[(ta + 3) & 3][nt] = kwf[(size_t)((ta + 3) * 4 + nt) * 64 + l];
        }

        // batched A-fragment reads (one lgkm group)
        bf16x8 af[4];
        #pragma unroll
        for (int r = 0; r < 4; ++r) {
            const int y10 = yloc + (r >> 1) + b;
            const int zp = 16 * (r & 1) + lr + c;
            const int byte = ((a * 10 + y10) * 34 + zp) * 64 + ((lg ^ ((zp >> 1) & 3)) << 4);
            af[r] = *reinterpret_cast<const bf16x8*>(lxc + byte);
        }

        #pragma unroll
        for (int r = 0; r < 4; ++r)
            #pragma unroll
            for (int nt = 0; nt < 4; ++nt)
                acc[r][nt] = __builtin_amdgcn_mfma_f32_16x16x32_bf16(
                    af[r], bring[ta & 3][nt], acc[r][nt], 0, 0, 0);
    }

    // ---- epilogue: C col = lane&15 (out-ch), row = (lane>>4)*4 + reg (z) ----
    float* ob = out + ((size_t)(((n * 32 + X) * 32 + Y0 + yloc) * 32) << 6);
    #pragma unroll
    for (int r = 0; r < 4; ++r) {
        float* oy = ob + (size_t)(r >> 1) * 2048;
        #pragma unroll
        for (int nt = 0; nt < 4; ++nt)
            #pragma unroll
            for (int reg = 0; reg < 4; ++reg) {
                const int z = 16 * (r & 1) + 4 * lg + reg;
                oy[z * 64 + nt * 16 + lr] = acc[r][nt][reg];
            }
    }
}

extern "C" void kernel_launch(void* const* d_in, const int* in_sizes, int n_in,
                              void* d_out, int out_size, void* d_ws, size_t ws_size,
                              hipStream_t stream) {
    const float* x    = (const float*)d_in[0];
    const float* wl0  = (const float*)d_in[1];
    const float* wl1  = (const float*)d_in[2];
    const float* w000 = (const float*)d_in[3];
    const float* w011 = (const float*)d_in[4];
    const float* w101 = (const float*)d_in[5];
    const float* w110 = (const float*)d_in[6];
    float* out = (float*)d_out;

    unsigned short* kw = (unsigned short*)d_ws;
    const size_t KWB = 77824;               // 19*4*64*8*2
    const size_t XBB = 16777216ull;         // 8*32^3*32*2

    if (ws_size >= KWB + XBB) {
        unsigned short* xb = (unsigned short*)((char*)d_ws + KWB);
        prep_all<<<dim3(4096 + 19), dim3(256), 0, stream>>>(
            x, wl0, wl1, w000, w011, w101, w110, xb, kw, 4096);
        conv_mfma<true><<<dim3(1024), dim3(256), 0, stream>>>(x, xb, kw, out);
    } else {
        prep_all<<<dim3(19), dim3(256), 0, stream>>>(
            x, wl0, wl1, w000, w011, w101, w110, nullptr, kw, 0);
        conv_mfma<false><<<dim3(1024), dim3(256), 0, stream>>>(x, nullptr, kw, out);
    }
}